// Round 14
// baseline (105.414 us; speedup 1.0000x reference)
//
#include <hip/hip_runtime.h>
#include <hip/hip_bf16.h>

// MultiHeadAttention fused pipeline for MI355X (gfx950).
// B=8, N=1024, DIM=192, HEADS=3, DH=64.
//
// Workspace layout (bytes):
//   partial @ 0         : 24,576     [bh][256] f32 SE-pool partials
//   wt      @ 3,145,728 : 221,184    W_qkv^T bf16 [576][192]
//   q       @ 3,366,912 : 3,145,728  [bh][n][d] bf16 (PRE-SCALED by 0.125)
//   k       @ 6,512,640 : 3,145,728  [bh][n][d] bf16
//   vt      @ 9,658,368 : 3,145,728  [bh] fragment-major V: colt*16384+kt*512+lane*8
//   a       @ 12,804,096: 50,331,648 [bh][i][j] bf16
//   o       @ 63,135,744: 6,291,456  [n][h*64+d] f32

typedef unsigned short u16;
typedef unsigned int u32;
using f32x4 = __attribute__((ext_vector_type(4))) float;
using short8 = __attribute__((ext_vector_type(8))) short;

#if defined(__has_builtin)
#if __has_builtin(__builtin_amdgcn_fdot2_f32_bf16)
#define USE_DOT2 1
#endif
#endif
#ifndef USE_DOT2
#define USE_DOT2 0
#endif

__device__ inline u16 f2bf(float f) {
  u32 u = __builtin_bit_cast(u32, f);
  u32 r = (u + 0x7FFFu + ((u >> 16) & 1u)) >> 16;
  return (u16)r;
}
__device__ inline float bf2f(u16 v) {
  u32 u = ((u32)v) << 16;
  return __builtin_bit_cast(float, u);
}
// packed pair convert: compiler emits v_cvt_pk_bf16_f32 (RNE), low16 = a
__device__ inline u32 pkbf(float a, float b) {
  union { __hip_bfloat162 h; u32 u; } cv;
  cv.h = __float22bfloat162_rn(make_float2(a, b));
  return cv.u;
}
__device__ inline short8 asfrag(uint4 v) { return __builtin_bit_cast(short8, v); }

#if USE_DOT2
typedef __attribute__((ext_vector_type(2))) __bf16 bf16x2;
// d = p.x*w.x + p.y*w.y + c  (bf16 inputs, f32 accumulate)
__device__ inline float dot2(u32 p, u32 w, float c) {
  return __builtin_amdgcn_fdot2_f32_bf16(__builtin_bit_cast(bf16x2, p),
                                         __builtin_bit_cast(bf16x2, w), c, false);
}
#endif

// ---------------- K0: transpose W_qkv -> wt bf16 [576][192] ----------------
__global__ __launch_bounds__(256) void mha_wt(const float* __restrict__ wq,
                                              u16* __restrict__ wt) {
  int i = blockIdx.x * 256 + threadIdx.x;
  int c = i / 192, kk = i - c * 192;
  wt[i] = f2bf(wq[(size_t)kk * 576 + c]);
}

// ---------------- K1: qkv projection (wt staged in LDS) ----------------
// grid (128,3): x-block = 64 rows; y: 0->q (pre-scaled 0.125), 1->k, 2->v (frag-major).
__global__ __launch_bounds__(256) void mha_qkv(const float* __restrict__ x,
                                               const u16* __restrict__ wt,
                                               u16* __restrict__ q,
                                               u16* __restrict__ kmat,
                                               u16* __restrict__ vt) {
  __shared__ u16 tile[64][72];
  __shared__ u16 wtile[64 * 200];
  int mb = blockIdx.x, gy = blockIdx.y;
  int tid = threadIdx.x, w = tid >> 6, l = tid & 63;
  int lr = l & 15, lg = l >> 4;
  int m0 = mb * 64 + w * 16;
  const float* xrow = x + (size_t)(m0 + lr) * 192;
  float scl = (gy == 0) ? 0.125f : 1.0f;
  uint4 af[6];
#pragma unroll
  for (int s = 0; s < 6; ++s) {
    float4 a0 = *(const float4*)(xrow + s * 32 + lg * 8);
    float4 a1 = *(const float4*)(xrow + s * 32 + lg * 8 + 4);
    uint4 p;
    p.x = pkbf(a0.x, a0.y);
    p.y = pkbf(a0.z, a0.w);
    p.z = pkbf(a1.x, a1.y);
    p.w = pkbf(a1.z, a1.w);
    af[s] = p;
  }
  int b = mb >> 4, n0 = (mb & 15) << 6;
  for (int i = 0; i < 3; ++i) {
    int nt = gy * 3 + i;
    // ---- stage wt rows nt*64..+63 into wtile (coalesced) ----
    const u16* wsrc = wt + (size_t)nt * 64 * 192;
#pragma unroll
    for (int it2 = 0; it2 < 6; ++it2) {
      int idx = tid + it2 * 256;        // 1536 uint4-chunks: 64 rows x 24
      int row = idx / 24, ch = idx - row * 24;
      uint4 vv = *(const uint4*)(wsrc + row * 192 + ch * 8);
      *(uint4*)&wtile[row * 200 + ch * 8] = vv;
    }
    __syncthreads();
#pragma unroll
    for (int ct = 0; ct < 4; ++ct) {
      const u16* wrow = &wtile[(ct * 16 + lr) * 200];
      f32x4 acc = {0.f, 0.f, 0.f, 0.f};
#pragma unroll
      for (int s = 0; s < 6; ++s) {
        uint4 bf = *(const uint4*)(wrow + s * 32 + lg * 8);
        acc = __builtin_amdgcn_mfma_f32_16x16x32_bf16(asfrag(af[s]), asfrag(bf), acc, 0, 0, 0);
      }
#pragma unroll
      for (int r = 0; r < 4; ++r) tile[w * 16 + 4 * lg + r][ct * 16 + lr] = f2bf(acc[r] * scl);
    }
    __syncthreads();
    size_t bh = (size_t)(b * 3 + i);
    if (gy < 2) {
      u16* dst = (gy == 0 ? q : kmat) + bh * 65536;
#pragma unroll
      for (int it = 0; it < 2; ++it) {
        int id = tid + it * 256;
        int rr = id >> 3, ch = id & 7;
        uint4 vv = *(const uint4*)&tile[rr][ch * 8];
        *(uint4*)(dst + (size_t)(n0 + rr) * 64 + ch * 8) = vv;
      }
    } else {
      // V fragment-major: v[n][d] at (d>>4)*16384 + (n>>5)*512 + ((n>>3)&3)*128 + (d&15)*8 + (n&7)
      u16* dst = vt + bh * 65536;
#pragma unroll
      for (int it = 0; it < 2; ++it) {
        int id = tid + it * 256;
        int d = id >> 3, ch = id & 7;
        u16 pk[8];
#pragma unroll
        for (int e = 0; e < 8; ++e) pk[e] = tile[ch * 8 + e][d];
        int n = n0 + ch * 8;
        int addr = (d >> 4) * 16384 + (n >> 5) * 512 + (ch & 3) * 128 + (d & 15) * 8;
        *(uint4*)(dst + addr) = *(const uint4*)pk;
      }
    }
    __syncthreads();
  }
}

// ---------------- K2: fused QK^T + conv1+bn+relu + conv2+bn+relu + pool ----------------
// grid 6144 = bh(24)*rowblock(64)*colstrip(4); 256 threads (4 waves). 16x256 tile.
// S bf16 [20][268] rows r0-2..r0+17, local cols 0..259 = j s0-2..s0+257 (260..263 zeroed).
// C1 bf16 [18][268] rows r0-1..r0+16, local cols 0..259.
// LDS ~20.4KB -> 7 blocks/CU (28 waves): inter-block overlap covers phase barriers.
#define SW 268
__global__ __launch_bounds__(256) void mha_qkconv(
    const u16* __restrict__ q, const u16* __restrict__ kmat,
    const float* __restrict__ c1w, const float* __restrict__ c1b,
    const float* __restrict__ g1, const float* __restrict__ bb1,
    const float* __restrict__ c2w, const float* __restrict__ c2b,
    const float* __restrict__ g2, const float* __restrict__ bb2,
    u16* __restrict__ a, float* __restrict__ partial) {
  __shared__ u16 S[20 * SW];
  __shared__ u16 C1[18 * SW];
  __shared__ float wred[4];
  int bid = blockIdx.x;
  int st = bid & 3, rb = (bid >> 2) & 63, bh = bid >> 8;
  int h = bh - (bh / 3) * 3;
  int r0 = rb * 16, s0 = st * 256;
  bool edge = (rb == 0) | (rb == 63) | (st == 0) | (st == 3);
  int tid = threadIdx.x, w = tid >> 6, l = tid & 63;
  int lr = l & 15, lg = l >> 4;
  const u16* qb = q + (size_t)bh * 65536;
  const u16* kb = kmat + (size_t)bh * 65536;
  // ---- phase 1: T = K*Q^T (each lane holds 4 consecutive S-cols) ----
  uint4 bq[2][2];
  if (edge) {
#pragma unroll
    for (int it = 0; it < 2; ++it) {
      int gi = r0 - 2 + 16 * it + lr;
      bool ok = (gi >= 0) && (gi < 1024);
#pragma unroll
      for (int kk = 0; kk < 2; ++kk)
        bq[it][kk] = ok ? *(const uint4*)(qb + (size_t)gi * 64 + kk * 32 + lg * 8)
                        : make_uint4(0, 0, 0, 0);
    }
  } else {
#pragma unroll
    for (int it = 0; it < 2; ++it) {
      const u16* qr = qb + (size_t)(r0 - 2 + 16 * it + lr) * 64;
      bq[it][0] = *(const uint4*)(qr + lg * 8);
      bq[it][1] = *(const uint4*)(qr + 32 + lg * 8);
    }
  }
#pragma unroll
  for (int t = 0; t < 5; ++t) {
    if (t == 4 && w != 0) break;
    int jt = w + 4 * t;  // 0..16
    int gj = s0 - 2 + 16 * jt + lr;
    uint4 ak0, ak1;
    if (edge) {
      bool ok = (gj >= 0) && (gj < 1024);
      ak0 = ok ? *(const uint4*)(kb + (size_t)gj * 64 + lg * 8) : make_uint4(0, 0, 0, 0);
      ak1 = ok ? *(const uint4*)(kb + (size_t)gj * 64 + 32 + lg * 8) : make_uint4(0, 0, 0, 0);
    } else {
      const u16* kr = kb + (size_t)gj * 64;
      ak0 = *(const uint4*)(kr + lg * 8);
      ak1 = *(const uint4*)(kr + 32 + lg * 8);
    }
    int sj = 16 * jt + 4 * lg;
#pragma unroll
    for (int it = 0; it < 2; ++it) {
      f32x4 acc = {0.f, 0.f, 0.f, 0.f};
      acc = __builtin_amdgcn_mfma_f32_16x16x32_bf16(asfrag(ak0), asfrag(bq[it][0]), acc, 0, 0, 0);
      acc = __builtin_amdgcn_mfma_f32_16x16x32_bf16(asfrag(ak1), asfrag(bq[it][1]), acc, 0, 0, 0);
      int si = 16 * it + lr;
      if (si < 20 && sj < 260) {
        uint2 st2;
        st2.x = pkbf(acc[0], acc[1]);
        st2.y = pkbf(acc[2], acc[3]);
        *(uint2*)&S[si * SW + sj] = st2;
      }
    }
  }
  // zero the 4-col tail (cols 260..263) so the x0 dot2 taps never read NaN garbage
  if (tid < 20) *(uint2*)&S[tid * SW + 260] = make_uint2(0, 0);
  __syncthreads();
  // ---- phase 2: conv1+bn+relu -> C1 (bf16), vertical rolling window ----
  float sc1 = g1[h] / sqrtf(1.00001f);
#if USE_DOT2
  u32 wp01a[3], wp2za[3];
#pragma unroll
  for (int di = 0; di < 3; ++di) {
    wp01a[di] = pkbf(c1w[h * 9 + di * 3 + 0] * sc1, c1w[h * 9 + di * 3 + 1] * sc1);
    wp2za[di] = pkbf(c1w[h * 9 + di * 3 + 2] * sc1, 0.f);
  }
#else
  float wc1[9];
#pragma unroll
  for (int i = 0; i < 9; ++i) wc1[i] = c1w[h * 9 + i] * sc1;
#endif
  float bias1 = c1b[h] * sc1 + bb1[h];
  for (int job = tid; job < 260; job += 256) {
    int rs = job / 65;
    int cg = job - rs * 65;
    int base = rs * 5;               // rs=3 -> base 15 (3 rows)
    int nr = (rs < 3) ? 5 : 3;
    int c0 = cg * 4;
    float cm[4];
    if (edge) {
#pragma unroll
      for (int e = 0; e < 4; ++e) {
        int gc = s0 - 1 + c0 + e;
        cm[e] = (gc >= 0 && gc < 1024) ? 1.f : 0.f;
      }
    }
#if USE_DOT2
    u32 wu[3][4], wsf[3][3];
#pragma unroll
    for (int rr = 0; rr < 2; ++rr) {
      uint2 d0 = *(const uint2*)&S[(base + rr) * SW + c0];
      uint2 d1 = *(const uint2*)&S[(base + rr) * SW + c0 + 4];
      wu[rr][0] = d0.x; wu[rr][1] = d0.y; wu[rr][2] = d1.x; wu[rr][3] = d1.y;
      wsf[rr][0] = __builtin_amdgcn_alignbit(d0.y, d0.x, 16);
      wsf[rr][1] = __builtin_amdgcn_alignbit(d1.x, d0.y, 16);
      wsf[rr][2] = __builtin_amdgcn_alignbit(d1.y, d1.x, 16);
    }
#pragma unroll
    for (int i = 0; i < 5; ++i) {
      if (i >= nr) break;
      int ci = base + i;             // <= 17
      int wi = (i + 2) % 3;
      {
        uint2 d0 = *(const uint2*)&S[(ci + 2) * SW + c0];
        uint2 d1 = *(const uint2*)&S[(ci + 2) * SW + c0 + 4];
        wu[wi][0] = d0.x; wu[wi][1] = d0.y; wu[wi][2] = d1.x; wu[wi][3] = d1.y;
        wsf[wi][0] = __builtin_amdgcn_alignbit(d0.y, d0.x, 16);
        wsf[wi][1] = __builtin_amdgcn_alignbit(d1.x, d0.y, 16);
        wsf[wi][2] = __builtin_amdgcn_alignbit(d1.y, d1.x, 16);
      }
      float r0v = bias1, r1v = bias1, r2v = bias1, r3v = bias1;
#pragma unroll
      for (int di = 0; di < 3; ++di) {
        int sl = (i + di) % 3;
        r0v = dot2(wu[sl][0], wp01a[di], r0v);
        r0v = dot2(wu[sl][1], wp2za[di], r0v);
        r1v = dot2(wsf[sl][0], wp01a[di], r1v);
        r1v = dot2(wsf[sl][1], wp2za[di], r1v);
        r2v = dot2(wu[sl][1], wp01a[di], r2v);
        r2v = dot2(wu[sl][2], wp2za[di], r2v);
        r3v = dot2(wsf[sl][1], wp01a[di], r3v);
        r3v = dot2(wsf[sl][2], wp2za[di], r3v);
      }
      f32x4 res = {r0v, r1v, r2v, r3v};
      if (edge) {
        int gr = r0 - 1 + ci;
        float rm = (gr >= 0 && gr < 1024) ? 1.f : 0.f;
#pragma unroll
        for (int e = 0; e < 4; ++e) res[e] = fmaxf(res[e], 0.f) * rm * cm[e];
      } else {
#pragma unroll
        for (int e = 0; e < 4; ++e) res[e] = fmaxf(res[e], 0.f);
      }
      uint2 st2;
      st2.x = pkbf(res[0], res[1]);
      st2.y = pkbf(res[2], res[3]);
      *(uint2*)&C1[ci * SW + c0] = st2;
    }
#else
    float win[3][6];
#pragma unroll
    for (int rr = 0; rr < 2; ++rr) {
      uint2 d0 = *(const uint2*)&S[(base + rr) * SW + c0];
      uint2 d1 = *(const uint2*)&S[(base + rr) * SW + c0 + 4];
      const u16* p0 = (const u16*)&d0;
      const u16* p1 = (const u16*)&d1;
#pragma unroll
      for (int e = 0; e < 4; ++e) win[rr][e] = bf2f(p0[e]);
      win[rr][4] = bf2f(p1[0]);
      win[rr][5] = bf2f(p1[1]);
    }
#pragma unroll
    for (int i = 0; i < 5; ++i) {
      if (i >= nr) break;
      int ci = base + i;
      int srow = ci + 2;
      uint2 d0 = *(const uint2*)&S[srow * SW + c0];
      uint2 d1 = *(const uint2*)&S[srow * SW + c0 + 4];
      const u16* p0 = (const u16*)&d0;
      const u16* p1 = (const u16*)&d1;
      int wi = (i + 2) % 3;
#pragma unroll
      for (int e = 0; e < 4; ++e) win[wi][e] = bf2f(p0[e]);
      win[wi][4] = bf2f(p1[0]);
      win[wi][5] = bf2f(p1[1]);
      const float* v0 = win[i % 3];
      const float* v1 = win[(i + 1) % 3];
      const float* v2 = win[(i + 2) % 3];
      f32x4 res = {bias1, bias1, bias1, bias1};
#pragma unroll
      for (int e = 0; e < 4; ++e) {
        res[e] += wc1[0] * v0[e] + wc1[1] * v0[e + 1] + wc1[2] * v0[e + 2];
        res[e] += wc1[3] * v1[e] + wc1[4] * v1[e + 1] + wc1[5] * v1[e + 2];
        res[e] += wc1[6] * v2[e] + wc1[7] * v2[e + 1] + wc1[8] * v2[e + 2];
      }
      if (edge) {
        int gr = r0 - 1 + ci;
        float rm = (gr >= 0 && gr < 1024) ? 1.f : 0.f;
#pragma unroll
        for (int e = 0; e < 4; ++e) res[e] = fmaxf(res[e], 0.f) * rm * cm[e];
      } else {
#pragma unroll
        for (int e = 0; e < 4; ++e) res[e] = fmaxf(res[e], 0.f);
      }
      uint2 st2;
      st2.x = pkbf(res[0], res[1]);
      st2.y = pkbf(res[2], res[3]);
      *(uint2*)&C1[ci * SW + c0] = st2;
    }
#endif
  }
  __syncthreads();
  // ---- phase 3: conv2+bn+relu -> a (bf16 global) + pool, rolling window ----
  float sc2 = g2[h] / sqrtf(1.00001f);
#if USE_DOT2
  u32 wp01b[3], wp2zb[3];
#pragma unroll
  for (int di = 0; di < 3; ++di) {
    wp01b[di] = pkbf(c2w[h * 9 + di * 3 + 0] * sc2, c2w[h * 9 + di * 3 + 1] * sc2);
    wp2zb[di] = pkbf(c2w[h * 9 + di * 3 + 2] * sc2, 0.f);
  }
#else
  float wc2[9];
#pragma unroll
  for (int i = 0; i < 9; ++i) wc2[i] = c2w[h * 9 + i] * sc2;
#endif
  float bias2 = c2b[h] * sc2 + bb2[h];
  int rs3 = tid >> 6, cg3 = tid & 63;
  int j0 = cg3 * 4;
  int rbase = rs3 * 4;
  float lsum = 0.f;
  u16* ab = a + (size_t)bh * 1048576 + (size_t)(r0 + rbase) * 1024 + s0 + j0;
#if USE_DOT2
  u32 wu2[3][4], wsf2[3][3];
#pragma unroll
  for (int rr = 0; rr < 2; ++rr) {
    uint2 d0 = *(const uint2*)&C1[(rbase + rr) * SW + j0];
    uint2 d1 = *(const uint2*)&C1[(rbase + rr) * SW + j0 + 4];
    wu2[rr][0] = d0.x; wu2[rr][1] = d0.y; wu2[rr][2] = d1.x; wu2[rr][3] = d1.y;
    wsf2[rr][0] = __builtin_amdgcn_alignbit(d0.y, d0.x, 16);
    wsf2[rr][1] = __builtin_amdgcn_alignbit(d1.x, d0.y, 16);
    wsf2[rr][2] = __builtin_amdgcn_alignbit(d1.y, d1.x, 16);
  }
#pragma unroll
  for (int i = 0; i < 4; ++i) {
    int wi = (i + 2) % 3;
    {
      uint2 d0 = *(const uint2*)&C1[(rbase + i + 2) * SW + j0];
      uint2 d1 = *(const uint2*)&C1[(rbase + i + 2) * SW + j0 + 4];
      wu2[wi][0] = d0.x; wu2[wi][1] = d0.y; wu2[wi][2] = d1.x; wu2[wi][3] = d1.y;
      wsf2[wi][0] = __builtin_amdgcn_alignbit(d0.y, d0.x, 16);
      wsf2[wi][1] = __builtin_amdgcn_alignbit(d1.x, d0.y, 16);
      wsf2[wi][2] = __builtin_amdgcn_alignbit(d1.y, d1.x, 16);
    }
    float r0v = bias2, r1v = bias2, r2v = bias2, r3v = bias2;
#pragma unroll
    for (int di = 0; di < 3; ++di) {
      int sl = (i + di) % 3;
      r0v = dot2(wu2[sl][0], wp01b[di], r0v);
      r0v = dot2(wu2[sl][1], wp2zb[di], r0v);
      r1v = dot2(wsf2[sl][0], wp01b[di], r1v);
      r1v = dot2(wsf2[sl][1], wp2zb[di], r1v);
      r2v = dot2(wu2[sl][1], wp01b[di], r2v);
      r2v = dot2(wu2[sl][2], wp2zb[di], r2v);
      r3v = dot2(wsf2[sl][1], wp01b[di], r3v);
      r3v = dot2(wsf2[sl][2], wp2zb[di], r3v);
    }
    float vals[4] = {fmaxf(r0v, 0.f), fmaxf(r1v, 0.f), fmaxf(r2v, 0.f), fmaxf(r3v, 0.f)};
    lsum += vals[0] + vals[1] + vals[2] + vals[3];
    uint2 st2;
    st2.x = pkbf(vals[0], vals[1]);
    st2.y = pkbf(vals[2], vals[3]);
    *(uint2*)(ab + (size_t)i * 1024) = st2;
  }
#else
  float win2[3][6];
#pragma unroll
  for (int rr = 0; rr < 2; ++rr) {
    uint2 d0 = *(const uint2*)&C1[(rbase + rr) * SW + j0];
    uint2 d1 = *(const uint2*)&C1[(rbase + rr) * SW + j0 + 4];
    const u16* p0 = (const u16*)&d0;
    const u16* p1 = (const u16*)&d1;
#pragma unroll
    for (int e = 0; e < 4; ++e) win2[rr][e] = bf2f(p0[e]);
    win2[rr][4] = bf2f(p1[0]);
    win2[rr][5] = bf2f(p1[1]);
  }
#pragma unroll
  for (int i = 0; i < 4; ++i) {
    int crow = rbase + i + 2;
    uint2 d0 = *(const uint2*)&C1[crow * SW + j0];
    uint2 d1 = *(const uint2*)&C1[crow * SW + j0 + 4];
    const u16* p0 = (const u16*)&d0;
    const u16* p1 = (const u16*)&d1;
    int wi = (i + 2) % 3;
#pragma unroll
    for (int e = 0; e < 4; ++e) win2[wi][e] = bf2f(p0[e]);
    win2[wi][4] = bf2f(p1[0]);
    win2[wi][5] = bf2f(p1[1]);
    const float* v0 = win2[i % 3];
    const float* v1 = win2[(i + 1) % 3];
    const float* v2 = win2[(i + 2) % 3];
    f32x4 res = {bias2, bias2, bias2, bias2};
    float vals[4];
#pragma unroll
    for (int e = 0; e < 4; ++e) {
      res[e] += wc2[0] * v0[e] + wc2[1] * v0[e + 1] + wc2[2] * v0[e + 2];
      res[e] += wc2[3] * v1[e] + wc2[4] * v1[e + 1] + wc2[5] * v1[e + 2];
      res[e] += wc2[6] * v2[e] + wc2[7] * v2[e + 1] + wc2[8] * v2[e + 2];
      vals[e] = fmaxf(res[e], 0.f);
      lsum += vals[e];
    }
    uint2 st2;
    st2.x = pkbf(vals[0], vals[1]);
    st2.y = pkbf(vals[2], vals[3]);
    *(uint2*)(ab + (size_t)i * 1024) = st2;
  }
#endif
#pragma unroll
  for (int off = 32; off; off >>= 1) lsum += __shfl_xor(lsum, off);
  if (l == 0) wred[w] = lsum;
  __syncthreads();
  if (tid == 0) {
    partial[bid] = wred[0] + wred[1] + wred[2] + wred[3];  // bid = bh*256 + rb*4 + st
  }
}

// ---------------- K3: SE gate + softmax(cw*a) + PV ----------------
// grid 1536 = bh(24)*rowblock(64 of 16 rows); 256 threads (4 waves).
// Static LDS ~32.9KB -> 4 blocks/CU. P 16x1024 bf16 (2048B row stride, 16B
// chunks XOR-swizzled by ((row&7)<<4)). a-loads prefetched before SE barrier.
__global__ __launch_bounds__(256) void mha_smpv(
    const u16* __restrict__ a, const u16* __restrict__ vt,
    const float* __restrict__ partial,
    const float* __restrict__ caw1, const float* __restrict__ cab1,
    const float* __restrict__ caw2, const float* __restrict__ cab2,
    float* __restrict__ o) {
  __shared__ char smem[32768];
  __shared__ float reds[16];
  __shared__ float pm[3];
  int bid = blockIdx.x;
  int rb = bid & 63, bh = bid >> 6;
  int b = bh / 3, h = bh - 3 * b;
  int n0 = rb * 16;
  int tid = threadIdx.x, w = tid >> 6, l = tid & 63;
  int row = tid >> 4, seg = tid & 15;
  // ---- prefetch the a-tile rows (independent of cw) ----
  const u16* arp = a + (size_t)bh * 1048576 + (size_t)(n0 + row) * 1024;
  uint4 av[8];
#pragma unroll
  for (int p = 0; p < 8; ++p) av[p] = *(const uint4*)(arp + p * 128 + seg * 8);
  // ---- SE pool: waves 0-2 reduce one head each (256 partials per bh) ----
  if (w < 3) {
    const float* pp = partial + (size_t)(b * 3 + w) * 256;
    float s = pp[l] + pp[l + 64] + pp[l + 128] + pp[l + 192];
#pragma unroll
    for (int off = 32; off; off >>= 1) s += __shfl_xor(s, off);
    if (l == 0) pm[w] = s;
  }
  __syncthreads();
  float hid = fmaxf((pm[0] * caw1[0] + pm[1] * caw1[1] + pm[2] * caw1[2]) * (1.f / 1048576.f) +
                        cab1[0], 0.f);
  float cwv = 1.f / (1.f + __expf(-(hid * caw2[h] + cab2[h])));
  // ---- exp pass: row = tid>>4, seg = tid&15 (prefetched data) ----
  char* prow = smem + row * 2048;
  u32 swz = (row & 7) << 4;
  float rsum = 0.f;
#pragma unroll
  for (int p = 0; p < 8; ++p) {
    const u16* pv = (const u16*)&av[p];
    float ex[8];
#pragma unroll
    for (int e = 0; e < 8; ++e) {
      ex[e] = __expf(bf2f(pv[e]) * cwv);
      rsum += ex[e];
    }
    uint4 pkv;
    pkv.x = pkbf(ex[0], ex[1]);
    pkv.y = pkbf(ex[2], ex[3]);
    pkv.z = pkbf(ex[4], ex[5]);
    pkv.w = pkbf(ex[6], ex[7]);
    int chunk = p * 16 + seg;
    *(uint4*)(prow + ((chunk << 4) ^ swz)) = pkv;
  }
  rsum += __shfl_xor(rsum, 1);
  rsum += __shfl_xor(rsum, 2);
  rsum += __shfl_xor(rsum, 4);
  rsum += __shfl_xor(rsum, 8);
  if (seg == 0) reds[row] = rsum;
  __syncthreads();
  // ---- PV: wave w = colt (0..3), 16x16 tile, K=1024; V frag-major coalesced ----
  int colt = w;
  int lr = l & 15, lg = l >> 4;
  const u16* vb = vt + (size_t)bh * 65536 + colt * 16384 + l * 8;
  const char* al = smem + lr * 2048;
  u32 aswz = (lr & 7) << 4;
  f32x4 accA = {0.f, 0.f, 0.f, 0.f};
  f32x4 accB = {0.f, 0.f, 0.f, 0.f};
  for (int kt = 0; kt < 32; kt += 2) {
    uint4 af0 = *(const uint4*)(al + ((((kt << 2) + lg) << 4) ^ aswz));
    uint4 bf0 = *(const uint4*)(vb + kt * 512);
    uint4 af1 = *(const uint4*)(al + (((((kt + 1) << 2) + lg) << 4) ^ aswz));
    uint4 bf1 = *(const uint4*)(vb + (kt + 1) * 512);
    accA = __builtin_amdgcn_mfma_f32_16x16x32_bf16(asfrag(af0), asfrag(bf0), accA, 0, 0, 0);
    accB = __builtin_amdgcn_mfma_f32_16x16x32_bf16(asfrag(af1), asfrag(bf1), accB, 0, 0, 0);
  }
  f32x4 acc = accA + accB;
  float* ob = o + (size_t)(b * 1024 + n0) * 192 + h * 64 + colt * 16 + lr;
#pragma unroll
  for (int r = 0; r < 4; ++r) {
    int rr = 4 * lg + r;
    ob[(size_t)rr * 192] = acc[r] / reds[rr];
  }
}

// ---------------- K4: output projection (fp32, W staged in LDS) ----------------
// grid (128, 3); 256 threads; each thread a 4x4 output tile.
__global__ __launch_bounds__(256) void mha_proj(const float* __restrict__ o,
                                                const float* __restrict__ W,
                                                const float* __restrict__ bo,
                                                float* __restrict__ out) {
  __shared__ float wlds[192 * 64];
  int nb = blockIdx.x, cb = blockIdx.y;
  int t = threadIdx.x;
#pragma unroll
  for (int it = 0; it < 12; ++it) {
    int idx = t + it * 256;          // 3072 f32x4-chunks: 192 rows x 16
    int row = idx >> 4, ch = idx & 15;
    *(f32x4*)&wlds[row * 64 + ch * 4] =
        *(const f32x4*)(W + (size_t)row * 192 + cb * 64 + ch * 4);
  }
  __syncthreads();
  int r0 = nb * 64 + (t >> 4) * 4;
  int c0l = (t & 15) * 4;
  const float* orow = o + (size_t)r0 * 192;
  float acc[4][4];
#pragma unroll
  for (int i = 0; i < 4; ++i)
#pragma unroll
    for (int j = 0; j < 4; ++j) acc[i][j] = 0.f;
  for (int kx = 0; kx < 192; kx += 4) {
    f32x4 ov[4], wv[4];
#pragma unroll
    for (int i = 0; i < 4; ++i) ov[i] = *(const f32x4*)(orow + (size_t)i * 192 + kx);
#pragma unroll
    for (int kk = 0; kk < 4; ++kk) wv[kk] = *(const f32x4*)&wlds[(kx + kk) * 64 + c0l];
#pragma unroll
    for (int i = 0; i < 4; ++i)
#pragma unroll
      for (int kk = 0; kk < 4; ++kk)
#pragma unroll
        for (int j = 0; j < 4; ++j) acc[i][j] += ov[i][kk] * wv[kk][j];
  }
  int c0 = cb * 64 + c0l;
  f32x4 bv = *(const f32x4*)(bo + c0);
#pragma unroll
  for (int i = 0; i < 4; ++i) {
    f32x4 res = {acc[i][0] + bv[0], acc[i][1] + bv[1], acc[i][2] + bv[2], acc[i][3] + bv[3]};
    *(f32x4*)(out + (size_t)(r0 + i) * 192 + c0) = res;
  }
}

extern "C" void kernel_launch(void* const* d_in, const int* in_sizes, int n_in,
                              void* d_out, int out_size, void* d_ws, size_t ws_size,
                              hipStream_t stream) {
  (void)in_sizes; (void)n_in; (void)out_size; (void)ws_size;
  const float* x    = (const float*)d_in[0];
  const float* wqkv = (const float*)d_in[1];
  const float* c1w  = (const float*)d_in[2];
  const float* c1b  = (const float*)d_in[3];
  const float* g1   = (const float*)d_in[4];
  const float* b1   = (const float*)d_in[5];
  const float* c2w  = (const float*)d_in[6];
  const float* c2b  = (const float*)d_in[7];
  const float* g2   = (const float*)d_in[8];
  const float* b2   = (const float*)d_in[9];
  const float* caw1 = (const float*)d_in[10];
  const float* cab1 = (const float*)d_in[11];
  const float* caw2 = (const float*)d_in[12];
  const float* cab2 = (const float*)d_in[13];
  const float* wout = (const float*)d_in[14];
  const float* bout = (const float*)d_in[15];
  float* out = (float*)d_out;
  char* ws = (char*)d_ws;

  float* partial = (float*)(ws + 0);
  u16* wt = (u16*)(ws + 3145728);
  u16* q  = (u16*)(ws + 3366912);
  u16* k  = (u16*)(ws + 6512640);
  u16* vt = (u16*)(ws + 9658368);
  u16* a  = (u16*)(ws + 12804096);
  float* o = (float*)(ws + 63135744);

  mha_wt<<<432, 256, 0, stream>>>(wqkv, wt);
  mha_qkv<<<dim3(128, 3), 256, 0, stream>>>(x, wt, q, k, vt);
  mha_qkconv<<<6144, 256, 0, stream>>>(q, k, c1w, c1b, g1, b1, c2w, c2b, g2, b2, a, partial);
  mha_smpv<<<1536, 256, 0, stream>>>(a, vt, partial, caw1, cab1, caw2, cab2, o);
  mha_proj<<<dim3(128, 3), 256, 0, stream>>>(o, wout, bout, out);
}

// Round 15
// 95.167 us; speedup vs baseline: 1.1077x; 1.1077x over previous
//
#include <hip/hip_runtime.h>
#include <hip/hip_bf16.h>

// MultiHeadAttention fused pipeline for MI355X (gfx950).
// B=8, N=1024, DIM=192, HEADS=3, DH=64.
//
// Workspace layout (bytes):
//   partial @ 0         : 12,288     [bh][128] f32 SE-pool partials
//   wt      @ 3,145,728 : 221,184    W_qkv^T bf16 [576][192]
//   q       @ 3,366,912 : 3,145,728  [bh][n][d] bf16 (PRE-SCALED by 0.125)
//   k       @ 6,512,640 : 3,145,728  [bh][n][d] bf16
//   vt      @ 9,658,368 : 3,145,728  [bh] fragment-major V: colt*16384+kt*512+lane*8
//   a       @ 12,804,096: 50,331,648 [bh][i][j] bf16
//   o       @ 63,135,744: 6,291,456  [n][h*64+d] f32

typedef unsigned short u16;
typedef unsigned int u32;
using f32x4 = __attribute__((ext_vector_type(4))) float;
using short8 = __attribute__((ext_vector_type(8))) short;

#if defined(__has_builtin)
#if __has_builtin(__builtin_amdgcn_fdot2_f32_bf16)
#define USE_DOT2 1
#endif
#endif
#ifndef USE_DOT2
#define USE_DOT2 0
#endif

__device__ inline u16 f2bf(float f) {
  u32 u = __builtin_bit_cast(u32, f);
  u32 r = (u + 0x7FFFu + ((u >> 16) & 1u)) >> 16;
  return (u16)r;
}
__device__ inline float bf2f(u16 v) {
  u32 u = ((u32)v) << 16;
  return __builtin_bit_cast(float, u);
}
// packed pair convert: compiler emits v_cvt_pk_bf16_f32 (RNE), low16 = a
__device__ inline u32 pkbf(float a, float b) {
  union { __hip_bfloat162 h; u32 u; } cv;
  cv.h = __float22bfloat162_rn(make_float2(a, b));
  return cv.u;
}
__device__ inline short8 asfrag(uint4 v) { return __builtin_bit_cast(short8, v); }

#if USE_DOT2
typedef __attribute__((ext_vector_type(2))) __bf16 bf16x2;
// d = p.x*w.x + p.y*w.y + c  (bf16 inputs, f32 accumulate)
__device__ inline float dot2(u32 p, u32 w, float c) {
  return __builtin_amdgcn_fdot2_f32_bf16(__builtin_bit_cast(bf16x2, p),
                                         __builtin_bit_cast(bf16x2, w), c, false);
}
#endif

// ---------------- K0: transpose W_qkv -> wt bf16 [576][192] ----------------
__global__ __launch_bounds__(256) void mha_wt(const float* __restrict__ wq,
                                              u16* __restrict__ wt) {
  int i = blockIdx.x * 256 + threadIdx.x;
  int c = i / 192, kk = i - c * 192;
  wt[i] = f2bf(wq[(size_t)kk * 576 + c]);
}

// ---------------- K1: qkv projection (wt staged in LDS) ----------------
// grid (128,3): x-block = 64 rows; y: 0->q (pre-scaled 0.125), 1->k, 2->v (frag-major).
__global__ __launch_bounds__(256) void mha_qkv(const float* __restrict__ x,
                                               const u16* __restrict__ wt,
                                               u16* __restrict__ q,
                                               u16* __restrict__ kmat,
                                               u16* __restrict__ vt) {
  __shared__ u16 tile[64][72];
  __shared__ u16 wtile[64 * 200];
  int mb = blockIdx.x, gy = blockIdx.y;
  int tid = threadIdx.x, w = tid >> 6, l = tid & 63;
  int lr = l & 15, lg = l >> 4;
  int m0 = mb * 64 + w * 16;
  const float* xrow = x + (size_t)(m0 + lr) * 192;
  float scl = (gy == 0) ? 0.125f : 1.0f;
  uint4 af[6];
#pragma unroll
  for (int s = 0; s < 6; ++s) {
    float4 a0 = *(const float4*)(xrow + s * 32 + lg * 8);
    float4 a1 = *(const float4*)(xrow + s * 32 + lg * 8 + 4);
    uint4 p;
    p.x = pkbf(a0.x, a0.y);
    p.y = pkbf(a0.z, a0.w);
    p.z = pkbf(a1.x, a1.y);
    p.w = pkbf(a1.z, a1.w);
    af[s] = p;
  }
  int b = mb >> 4, n0 = (mb & 15) << 6;
  for (int i = 0; i < 3; ++i) {
    int nt = gy * 3 + i;
    // ---- stage wt rows nt*64..+63 into wtile (coalesced) ----
    const u16* wsrc = wt + (size_t)nt * 64 * 192;
#pragma unroll
    for (int it2 = 0; it2 < 6; ++it2) {
      int idx = tid + it2 * 256;        // 1536 uint4-chunks: 64 rows x 24
      int row = idx / 24, ch = idx - row * 24;
      uint4 vv = *(const uint4*)(wsrc + row * 192 + ch * 8);
      *(uint4*)&wtile[row * 200 + ch * 8] = vv;
    }
    __syncthreads();
#pragma unroll
    for (int ct = 0; ct < 4; ++ct) {
      const u16* wrow = &wtile[(ct * 16 + lr) * 200];
      f32x4 acc = {0.f, 0.f, 0.f, 0.f};
#pragma unroll
      for (int s = 0; s < 6; ++s) {
        uint4 bf = *(const uint4*)(wrow + s * 32 + lg * 8);
        acc = __builtin_amdgcn_mfma_f32_16x16x32_bf16(asfrag(af[s]), asfrag(bf), acc, 0, 0, 0);
      }
#pragma unroll
      for (int r = 0; r < 4; ++r) tile[w * 16 + 4 * lg + r][ct * 16 + lr] = f2bf(acc[r] * scl);
    }
    __syncthreads();
    size_t bh = (size_t)(b * 3 + i);
    if (gy < 2) {
      u16* dst = (gy == 0 ? q : kmat) + bh * 65536;
#pragma unroll
      for (int it = 0; it < 2; ++it) {
        int id = tid + it * 256;
        int rr = id >> 3, ch = id & 7;
        uint4 vv = *(const uint4*)&tile[rr][ch * 8];
        *(uint4*)(dst + (size_t)(n0 + rr) * 64 + ch * 8) = vv;
      }
    } else {
      // V fragment-major: v[n][d] at (d>>4)*16384 + (n>>5)*512 + ((n>>3)&3)*128 + (d&15)*8 + (n&7)
      u16* dst = vt + bh * 65536;
#pragma unroll
      for (int it = 0; it < 2; ++it) {
        int id = tid + it * 256;
        int d = id >> 3, ch = id & 7;
        u16 pk[8];
#pragma unroll
        for (int e = 0; e < 8; ++e) pk[e] = tile[ch * 8 + e][d];
        int n = n0 + ch * 8;
        int addr = (d >> 4) * 16384 + (n >> 5) * 512 + (ch & 3) * 128 + (d & 15) * 8;
        *(uint4*)(dst + addr) = *(const uint4*)pk;
      }
    }
    __syncthreads();
  }
}

// ---------------- K2: fused QK^T + conv1+bn+relu + conv2+bn+relu + pool ----------------
// grid 3072 = bh(24)*rowblock(32)*colstrip(4); 512 threads (8 waves). 32x256 tile.
// XCD-aware bijective swizzle (3072%8==0): each XCD gets 384 consecutive logical
// bids = 3 complete bh's (q+k 768KB, L2-resident per XCD).
// S bf16 [36][268] rows r0-2..r0+33, local cols 0..259 = j s0-2..s0+257 (260..263 zeroed).
// C1 bf16 [34][268] rows r0-1..r0+32, local cols 0..259.
#define SW 268
__global__ __launch_bounds__(512) void mha_qkconv(
    const u16* __restrict__ q, const u16* __restrict__ kmat,
    const float* __restrict__ c1w, const float* __restrict__ c1b,
    const float* __restrict__ g1, const float* __restrict__ bb1,
    const float* __restrict__ c2w, const float* __restrict__ c2b,
    const float* __restrict__ g2, const float* __restrict__ bb2,
    u16* __restrict__ a, float* __restrict__ partial) {
  __shared__ u16 S[36 * SW];
  __shared__ u16 C1[34 * SW];
  __shared__ float wred[8];
  int bid0 = blockIdx.x;
  int bid = (bid0 & 7) * 384 + (bid0 >> 3);  // XCD-contiguous logical id
  int st = bid & 3, rb = (bid >> 2) & 31, bh = bid >> 7;
  int h = bh - (bh / 3) * 3;
  int r0 = rb * 32, s0 = st * 256;
  bool edge = (rb == 0) | (rb == 31) | (st == 0) | (st == 3);
  int tid = threadIdx.x, w = tid >> 6, l = tid & 63;
  int lr = l & 15, lg = l >> 4;
  const u16* qb = q + (size_t)bh * 65536;
  const u16* kb = kmat + (size_t)bh * 65536;
  // ---- phase 1: T = K*Q^T (each lane holds 4 consecutive S-cols) ----
  uint4 bq[3][2];
  if (edge) {
#pragma unroll
    for (int it = 0; it < 3; ++it) {
      int gi = r0 - 2 + 16 * it + lr;
      bool ok = (gi >= 0) && (gi < 1024);
#pragma unroll
      for (int kk = 0; kk < 2; ++kk)
        bq[it][kk] = ok ? *(const uint4*)(qb + (size_t)gi * 64 + kk * 32 + lg * 8)
                        : make_uint4(0, 0, 0, 0);
    }
  } else {
#pragma unroll
    for (int it = 0; it < 3; ++it) {
      const u16* qr = qb + (size_t)(r0 - 2 + 16 * it + lr) * 64;
      bq[it][0] = *(const uint4*)(qr + lg * 8);
      bq[it][1] = *(const uint4*)(qr + 32 + lg * 8);
    }
  }
#pragma unroll
  for (int t = 0; t < 3; ++t) {
    if (t == 2 && w != 0) break;
    int jt = (t < 2) ? (w + 8 * t) : 16;
    int gj = s0 - 2 + 16 * jt + lr;
    uint4 ak0, ak1;
    if (edge) {
      bool ok = (gj >= 0) && (gj < 1024);
      ak0 = ok ? *(const uint4*)(kb + (size_t)gj * 64 + lg * 8) : make_uint4(0, 0, 0, 0);
      ak1 = ok ? *(const uint4*)(kb + (size_t)gj * 64 + 32 + lg * 8) : make_uint4(0, 0, 0, 0);
    } else {
      const u16* kr = kb + (size_t)gj * 64;
      ak0 = *(const uint4*)(kr + lg * 8);
      ak1 = *(const uint4*)(kr + 32 + lg * 8);
    }
    int sj = 16 * jt + 4 * lg;
#pragma unroll
    for (int it = 0; it < 3; ++it) {
      f32x4 acc = {0.f, 0.f, 0.f, 0.f};
      acc = __builtin_amdgcn_mfma_f32_16x16x32_bf16(asfrag(ak0), asfrag(bq[it][0]), acc, 0, 0, 0);
      acc = __builtin_amdgcn_mfma_f32_16x16x32_bf16(asfrag(ak1), asfrag(bq[it][1]), acc, 0, 0, 0);
      int si = 16 * it + lr;
      if (si < 36 && sj < 260) {
        uint2 st2;
        st2.x = pkbf(acc[0], acc[1]);
        st2.y = pkbf(acc[2], acc[3]);
        *(uint2*)&S[si * SW + sj] = st2;
      }
    }
  }
  // zero the 4-col tail (cols 260..263) so the x0 dot2 taps never read NaN garbage
  if (tid < 36) *(uint2*)&S[tid * SW + 260] = make_uint2(0, 0);
  __syncthreads();
  // ---- phase 2: conv1+bn+relu -> C1 (bf16), vertical rolling window ----
  float sc1 = g1[h] / sqrtf(1.00001f);
#if USE_DOT2
  u32 wp01a[3], wp2za[3];
#pragma unroll
  for (int di = 0; di < 3; ++di) {
    wp01a[di] = pkbf(c1w[h * 9 + di * 3 + 0] * sc1, c1w[h * 9 + di * 3 + 1] * sc1);
    wp2za[di] = pkbf(c1w[h * 9 + di * 3 + 2] * sc1, 0.f);
  }
#else
  float wc1[9];
#pragma unroll
  for (int i = 0; i < 9; ++i) wc1[i] = c1w[h * 9 + i] * sc1;
#endif
  float bias1 = c1b[h] * sc1 + bb1[h];
  if (tid < 455) {
    int rs = tid / 65;
    int cg = tid - rs * 65;
    int base = rs * 5;
    int c0 = cg * 4;
    float cm[4];
    if (edge) {
#pragma unroll
      for (int e = 0; e < 4; ++e) {
        int gc = s0 - 1 + c0 + e;
        cm[e] = (gc >= 0 && gc < 1024) ? 1.f : 0.f;
      }
    }
#if USE_DOT2
    u32 wu[3][4], wsf[3][3];
#pragma unroll
    for (int rr = 0; rr < 2; ++rr) {
      uint2 d0 = *(const uint2*)&S[(base + rr) * SW + c0];
      uint2 d1 = *(const uint2*)&S[(base + rr) * SW + c0 + 4];
      wu[rr][0] = d0.x; wu[rr][1] = d0.y; wu[rr][2] = d1.x; wu[rr][3] = d1.y;
      wsf[rr][0] = __builtin_amdgcn_alignbit(d0.y, d0.x, 16);
      wsf[rr][1] = __builtin_amdgcn_alignbit(d1.x, d0.y, 16);
      wsf[rr][2] = __builtin_amdgcn_alignbit(d1.y, d1.x, 16);
    }
#pragma unroll
    for (int i = 0; i < 5; ++i) {
      int ci = base + i;
      if (ci >= 34) break;
      int wi = (i + 2) % 3;
      {
        uint2 d0 = *(const uint2*)&S[(ci + 2) * SW + c0];
        uint2 d1 = *(const uint2*)&S[(ci + 2) * SW + c0 + 4];
        wu[wi][0] = d0.x; wu[wi][1] = d0.y; wu[wi][2] = d1.x; wu[wi][3] = d1.y;
        wsf[wi][0] = __builtin_amdgcn_alignbit(d0.y, d0.x, 16);
        wsf[wi][1] = __builtin_amdgcn_alignbit(d1.x, d0.y, 16);
        wsf[wi][2] = __builtin_amdgcn_alignbit(d1.y, d1.x, 16);
      }
      float r0v = bias1, r1v = bias1, r2v = bias1, r3v = bias1;
#pragma unroll
      for (int di = 0; di < 3; ++di) {
        int sl = (i + di) % 3;
        r0v = dot2(wu[sl][0], wp01a[di], r0v);
        r0v = dot2(wu[sl][1], wp2za[di], r0v);
        r1v = dot2(wsf[sl][0], wp01a[di], r1v);
        r1v = dot2(wsf[sl][1], wp2za[di], r1v);
        r2v = dot2(wu[sl][1], wp01a[di], r2v);
        r2v = dot2(wu[sl][2], wp2za[di], r2v);
        r3v = dot2(wsf[sl][1], wp01a[di], r3v);
        r3v = dot2(wsf[sl][2], wp2za[di], r3v);
      }
      f32x4 res = {r0v, r1v, r2v, r3v};
      if (edge) {
        int gr = r0 - 1 + ci;
        float rm = (gr >= 0 && gr < 1024) ? 1.f : 0.f;
#pragma unroll
        for (int e = 0; e < 4; ++e) res[e] = fmaxf(res[e], 0.f) * rm * cm[e];
      } else {
#pragma unroll
        for (int e = 0; e < 4; ++e) res[e] = fmaxf(res[e], 0.f);
      }
      uint2 st2;
      st2.x = pkbf(res[0], res[1]);
      st2.y = pkbf(res[2], res[3]);
      *(uint2*)&C1[ci * SW + c0] = st2;
    }
#else
    float win[3][6];
#pragma unroll
    for (int rr = 0; rr < 2; ++rr) {
      uint2 d0 = *(const uint2*)&S[(base + rr) * SW + c0];
      uint2 d1 = *(const uint2*)&S[(base + rr) * SW + c0 + 4];
      const u16* p0 = (const u16*)&d0;
      const u16* p1 = (const u16*)&d1;
#pragma unroll
      for (int e = 0; e < 4; ++e) win[rr][e] = bf2f(p0[e]);
      win[rr][4] = bf2f(p1[0]);
      win[rr][5] = bf2f(p1[1]);
    }
#pragma unroll
    for (int i = 0; i < 5; ++i) {
      int ci = base + i;
      if (ci >= 34) break;
      int srow = ci + 2;
      uint2 d0 = *(const uint2*)&S[srow * SW + c0];
      uint2 d1 = *(const uint2*)&S[srow * SW + c0 + 4];
      const u16* p0 = (const u16*)&d0;
      const u16* p1 = (const u16*)&d1;
      int wi = (i + 2) % 3;
#pragma unroll
      for (int e = 0; e < 4; ++e) win[wi][e] = bf2f(p0[e]);
      win[wi][4] = bf2f(p1[0]);
      win[wi][5] = bf2f(p1[1]);
      const float* v0 = win[i % 3];
      const float* v1 = win[(i + 1) % 3];
      const float* v2 = win[(i + 2) % 3];
      f32x4 res = {bias1, bias1, bias1, bias1};
#pragma unroll
      for (int e = 0; e < 4; ++e) {
        res[e] += wc1[0] * v0[e] + wc1[1] * v0[e + 1] + wc1[2] * v0[e + 2];
        res[e] += wc1[3] * v1[e] + wc1[4] * v1[e + 1] + wc1[5] * v1[e + 2];
        res[e] += wc1[6] * v2[e] + wc1[7] * v2[e + 1] + wc1[8] * v2[e + 2];
      }
      if (edge) {
        int gr = r0 - 1 + ci;
        float rm = (gr >= 0 && gr < 1024) ? 1.f : 0.f;
#pragma unroll
        for (int e = 0; e < 4; ++e) res[e] = fmaxf(res[e], 0.f) * rm * cm[e];
      } else {
#pragma unroll
        for (int e = 0; e < 4; ++e) res[e] = fmaxf(res[e], 0.f);
      }
      uint2 st2;
      st2.x = pkbf(res[0], res[1]);
      st2.y = pkbf(res[2], res[3]);
      *(uint2*)&C1[ci * SW + c0] = st2;
    }
#endif
  }
  __syncthreads();
  // ---- phase 3: conv2+bn+relu -> a (bf16 global) + pool, rolling window ----
  float sc2 = g2[h] / sqrtf(1.00001f);
#if USE_DOT2
  u32 wp01b[3], wp2zb[3];
#pragma unroll
  for (int di = 0; di < 3; ++di) {
    wp01b[di] = pkbf(c2w[h * 9 + di * 3 + 0] * sc2, c2w[h * 9 + di * 3 + 1] * sc2);
    wp2zb[di] = pkbf(c2w[h * 9 + di * 3 + 2] * sc2, 0.f);
  }
#else
  float wc2[9];
#pragma unroll
  for (int i = 0; i < 9; ++i) wc2[i] = c2w[h * 9 + i] * sc2;
#endif
  float bias2 = c2b[h] * sc2 + bb2[h];
  int rs3 = tid >> 6, cg3 = tid & 63;
  int j0 = cg3 * 4;
  int rbase = rs3 * 4;
  float lsum = 0.f;
  u16* ab = a + (size_t)bh * 1048576 + (size_t)(r0 + rbase) * 1024 + s0 + j0;
#if USE_DOT2
  u32 wu2[3][4], wsf2[3][3];
#pragma unroll
  for (int rr = 0; rr < 2; ++rr) {
    uint2 d0 = *(const uint2*)&C1[(rbase + rr) * SW + j0];
    uint2 d1 = *(const uint2*)&C1[(rbase + rr) * SW + j0 + 4];
    wu2[rr][0] = d0.x; wu2[rr][1] = d0.y; wu2[rr][2] = d1.x; wu2[rr][3] = d1.y;
    wsf2[rr][0] = __builtin_amdgcn_alignbit(d0.y, d0.x, 16);
    wsf2[rr][1] = __builtin_amdgcn_alignbit(d1.x, d0.y, 16);
    wsf2[rr][2] = __builtin_amdgcn_alignbit(d1.y, d1.x, 16);
  }
#pragma unroll
  for (int i = 0; i < 4; ++i) {
    int wi = (i + 2) % 3;
    {
      uint2 d0 = *(const uint2*)&C1[(rbase + i + 2) * SW + j0];
      uint2 d1 = *(const uint2*)&C1[(rbase + i + 2) * SW + j0 + 4];
      wu2[wi][0] = d0.x; wu2[wi][1] = d0.y; wu2[wi][2] = d1.x; wu2[wi][3] = d1.y;
      wsf2[wi][0] = __builtin_amdgcn_alignbit(d0.y, d0.x, 16);
      wsf2[wi][1] = __builtin_amdgcn_alignbit(d1.x, d0.y, 16);
      wsf2[wi][2] = __builtin_amdgcn_alignbit(d1.y, d1.x, 16);
    }
    float r0v = bias2, r1v = bias2, r2v = bias2, r3v = bias2;
#pragma unroll
    for (int di = 0; di < 3; ++di) {
      int sl = (i + di) % 3;
      r0v = dot2(wu2[sl][0], wp01b[di], r0v);
      r0v = dot2(wu2[sl][1], wp2zb[di], r0v);
      r1v = dot2(wsf2[sl][0], wp01b[di], r1v);
      r1v = dot2(wsf2[sl][1], wp2zb[di], r1v);
      r2v = dot2(wu2[sl][1], wp01b[di], r2v);
      r2v = dot2(wu2[sl][2], wp2zb[di], r2v);
      r3v = dot2(wsf2[sl][1], wp01b[di], r3v);
      r3v = dot2(wsf2[sl][2], wp2zb[di], r3v);
    }
    float vals[4] = {fmaxf(r0v, 0.f), fmaxf(r1v, 0.f), fmaxf(r2v, 0.f), fmaxf(r3v, 0.f)};
    lsum += vals[0] + vals[1] + vals[2] + vals[3];
    uint2 st2;
    st2.x = pkbf(vals[0], vals[1]);
    st2.y = pkbf(vals[2], vals[3]);
    *(uint2*)(ab + (size_t)i * 1024) = st2;
  }
#else
  float win2[3][6];
#pragma unroll
  for (int rr = 0; rr < 2; ++rr) {
    uint2 d0 = *(const uint2*)&C1[(rbase + rr) * SW + j0];
    uint2 d1 = *(const uint2*)&C1[(rbase + rr) * SW + j0 + 4];
    const u16* p0 = (const u16*)&d0;
    const u16* p1 = (const u16*)&d1;
#pragma unroll
    for (int e = 0; e < 4; ++e) win2[rr][e] = bf2f(p0[e]);
    win2[rr][4] = bf2f(p1[0]);
    win2[rr][5] = bf2f(p1[1]);
  }
#pragma unroll
  for (int i = 0; i < 4; ++i) {
    int crow = rbase + i + 2;
    uint2 d0 = *(const uint2*)&C1[crow * SW + j0];
    uint2 d1 = *(const uint2*)&C1[crow * SW + j0 + 4];
    const u16* p0 = (const u16*)&d0;
    const u16* p1 = (const u16*)&d1;
    int wi = (i + 2) % 3;
#pragma unroll
    for (int e = 0; e < 4; ++e) win2[wi][e] = bf2f(p0[e]);
    win2[wi][4] = bf2f(p1[0]);
    win2[wi][5] = bf2f(p1[1]);
    const float* v0 = win2[i % 3];
    const float* v1 = win2[(i + 1) % 3];
    const float* v2 = win2[(i + 2) % 3];
    f32x4 res = {bias2, bias2, bias2, bias2};
    float vals[4];
#pragma unroll
    for (int e = 0; e < 4; ++e) {
      res[e] += wc2[0] * v0[e] + wc2[1] * v0[e + 1] + wc2[2] * v0[e + 2];
      res[e] += wc2[3] * v1[e] + wc2[4] * v1[e + 1] + wc2[5] * v1[e + 2];
      res[e] += wc2[6] * v2[e] + wc2[7] * v2[e + 1] + wc2[8] * v2[e + 2];
      vals[e] = fmaxf(res[e], 0.f);
      lsum += vals[e];
    }
    uint2 st2;
    st2.x = pkbf(vals[0], vals[1]);
    st2.y = pkbf(vals[2], vals[3]);
    *(uint2*)(ab + (size_t)i * 1024) = st2;
  }
#endif
#pragma unroll
  for (int off = 32; off; off >>= 1) lsum += __shfl_xor(lsum, off);
  if (l == 0) wred[w] = lsum;
  __syncthreads();
  if (tid == 0) {
    float s = 0.f;
#pragma unroll
    for (int i = 0; i < 8; ++i) s += wred[i];
    partial[bid] = s;  // logical bid = bh*128 + rb*4 + st
  }
}

// ---------------- K3: SE gate + softmax(cw*a) + PV ----------------
// grid 1536 = bh(24)*rowblock(64 of 16 rows); 256 threads (4 waves).
// Static LDS ~32.9KB -> 4 blocks/CU. P 16x1024 bf16 (2048B row stride, 16B
// chunks XOR-swizzled by ((row&7)<<4)). a-loads prefetched before SE barrier.
__global__ __launch_bounds__(256) void mha_smpv(
    const u16* __restrict__ a, const u16* __restrict__ vt,
    const float* __restrict__ partial,
    const float* __restrict__ caw1, const float* __restrict__ cab1,
    const float* __restrict__ caw2, const float* __restrict__ cab2,
    float* __restrict__ o) {
  __shared__ char smem[32768];
  __shared__ float reds[16];
  __shared__ float pm[3];
  int bid = blockIdx.x;
  int rb = bid & 63, bh = bid >> 6;
  int b = bh / 3, h = bh - 3 * b;
  int n0 = rb * 16;
  int tid = threadIdx.x, w = tid >> 6, l = tid & 63;
  int row = tid >> 4, seg = tid & 15;
  // ---- prefetch the a-tile rows (independent of cw) ----
  const u16* arp = a + (size_t)bh * 1048576 + (size_t)(n0 + row) * 1024;
  uint4 av[8];
#pragma unroll
  for (int p = 0; p < 8; ++p) av[p] = *(const uint4*)(arp + p * 128 + seg * 8);
  // ---- SE pool: waves 0-2 reduce one head each (128 partials per bh) ----
  if (w < 3) {
    const float* pp = partial + (size_t)(b * 3 + w) * 128;
    float s = pp[l] + pp[l + 64];
#pragma unroll
    for (int off = 32; off; off >>= 1) s += __shfl_xor(s, off);
    if (l == 0) pm[w] = s;
  }
  __syncthreads();
  float hid = fmaxf((pm[0] * caw1[0] + pm[1] * caw1[1] + pm[2] * caw1[2]) * (1.f / 1048576.f) +
                        cab1[0], 0.f);
  float cwv = 1.f / (1.f + __expf(-(hid * caw2[h] + cab2[h])));
  // ---- exp pass: row = tid>>4, seg = tid&15 (prefetched data) ----
  char* prow = smem + row * 2048;
  u32 swz = (row & 7) << 4;
  float rsum = 0.f;
#pragma unroll
  for (int p = 0; p < 8; ++p) {
    const u16* pv = (const u16*)&av[p];
    float ex[8];
#pragma unroll
    for (int e = 0; e < 8; ++e) {
      ex[e] = __expf(bf2f(pv[e]) * cwv);
      rsum += ex[e];
    }
    uint4 pkv;
    pkv.x = pkbf(ex[0], ex[1]);
    pkv.y = pkbf(ex[2], ex[3]);
    pkv.z = pkbf(ex[4], ex[5]);
    pkv.w = pkbf(ex[6], ex[7]);
    int chunk = p * 16 + seg;
    *(uint4*)(prow + ((chunk << 4) ^ swz)) = pkv;
  }
  rsum += __shfl_xor(rsum, 1);
  rsum += __shfl_xor(rsum, 2);
  rsum += __shfl_xor(rsum, 4);
  rsum += __shfl_xor(rsum, 8);
  if (seg == 0) reds[row] = rsum;
  __syncthreads();
  // ---- PV: wave w = colt (0..3), 16x16 tile, K=1024; V frag-major coalesced ----
  int colt = w;
  int lr = l & 15, lg = l >> 4;
  const u16* vb = vt + (size_t)bh * 65536 + colt * 16384 + l * 8;
  const char* al = smem + lr * 2048;
  u32 aswz = (lr & 7) << 4;
  f32x4 accA = {0.f, 0.f, 0.f, 0.f};
  f32x4 accB = {0.f, 0.f, 0.f, 0.f};
  for (int kt = 0; kt < 32; kt += 2) {
    uint4 af0 = *(const uint4*)(al + ((((kt << 2) + lg) << 4) ^ aswz));
    uint4 bf0 = *(const uint4*)(vb + kt * 512);
    uint4 af1 = *(const uint4*)(al + (((((kt + 1) << 2) + lg) << 4) ^ aswz));
    uint4 bf1 = *(const uint4*)(vb + (kt + 1) * 512);
    accA = __builtin_amdgcn_mfma_f32_16x16x32_bf16(asfrag(af0), asfrag(bf0), accA, 0, 0, 0);
    accB = __builtin_amdgcn_mfma_f32_16x16x32_bf16(asfrag(af1), asfrag(bf1), accB, 0, 0, 0);
  }
  f32x4 acc = accA + accB;
  float* ob = o + (size_t)(b * 1024 + n0) * 192 + h * 64 + colt * 16 + lr;
#pragma unroll
  for (int r = 0; r < 4; ++r) {
    int rr = 4 * lg + r;
    ob[(size_t)rr * 192] = acc[r] / reds[rr];
  }
}

// ---------------- K4: output projection (fp32, W staged in LDS) ----------------
// grid (128, 3); 256 threads; each thread a 4x4 output tile.
__global__ __launch_bounds__(256) void mha_proj(const float* __restrict__ o,
                                                const float* __restrict__ W,
                                                const float* __restrict__ bo,
                                                float* __restrict__ out) {
  __shared__ float wlds[192 * 64];
  int nb = blockIdx.x, cb = blockIdx.y;
  int t = threadIdx.x;
#pragma unroll
  for (int it = 0; it < 12; ++it) {
    int idx = t + it * 256;          // 3072 f32x4-chunks: 192 rows x 16
    int row = idx >> 4, ch = idx & 15;
    *(f32x4*)&wlds[row * 64 + ch * 4] =
        *(const f32x4*)(W + (size_t)row * 192 + cb * 64 + ch * 4);
  }
  __syncthreads();
  int r0 = nb * 64 + (t >> 4) * 4;
  int c0l = (t & 15) * 4;
  const float* orow = o + (size_t)r0 * 192;
  float acc[4][4];
#pragma unroll
  for (int i = 0; i < 4; ++i)
#pragma unroll
    for (int j = 0; j < 4; ++j) acc[i][j] = 0.f;
  for (int kx = 0; kx < 192; kx += 4) {
    f32x4 ov[4], wv[4];
#pragma unroll
    for (int i = 0; i < 4; ++i) ov[i] = *(const f32x4*)(orow + (size_t)i * 192 + kx);
#pragma unroll
    for (int kk = 0; kk < 4; ++kk) wv[kk] = *(const f32x4*)&wlds[(kx + kk) * 64 + c0l];
#pragma unroll
    for (int i = 0; i < 4; ++i)
#pragma unroll
      for (int kk = 0; kk < 4; ++kk)
#pragma unroll
        for (int j = 0; j < 4; ++j) acc[i][j] += ov[i][kk] * wv[kk][j];
  }
  int c0 = cb * 64 + c0l;
  f32x4 bv = *(const f32x4*)(bo + c0);
#pragma unroll
  for (int i = 0; i < 4; ++i) {
    f32x4 res = {acc[i][0] + bv[0], acc[i][1] + bv[1], acc[i][2] + bv[2], acc[i][3] + bv[3]};
    *(f32x4*)(out + (size_t)(r0 + i) * 192 + c0) = res;
  }
}

extern "C" void kernel_launch(void* const* d_in, const int* in_sizes, int n_in,
                              void* d_out, int out_size, void* d_ws, size_t ws_size,
                              hipStream_t stream) {
  (void)in_sizes; (void)n_in; (void)out_size; (void)ws_size;
  const float* x    = (const float*)d_in[0];
  const float* wqkv = (const float*)d_in[1];
  const float* c1w  = (const float*)d_in[2];
  const float* c1b  = (const float*)d_in[3];
  const float* g1   = (const float*)d_in[4];
  const float* b1   = (const float*)d_in[5];
  const float* c2w  = (const float*)d_in[6];
  const float* c2b  = (const float*)d_in[7];
  const float* g2   = (const float*)d_in[8];
  const float* b2   = (const float*)d_in[9];
  const float* caw1 = (const float*)d_in[10];
  const float* cab1 = (const float*)d_in[11];
  const float* caw2 = (const float*)d_in[12];
  const float* cab2 = (const float*)d_in[13];
  const float* wout = (const float*)d_in[14];
  const float* bout = (const float*)d_in[15];
  float* out = (float*)d_out;
  char* ws = (char*)d_ws;

  float* partial = (float*)(ws + 0);
  u16* wt = (u16*)(ws + 3145728);
  u16* q  = (u16*)(ws + 3366912);
  u16* k  = (u16*)(ws + 6512640);
  u16* vt = (u16*)(ws + 9658368);
  u16* a  = (u16*)(ws + 12804096);
  float* o = (float*)(ws + 63135744);

  mha_wt<<<432, 256, 0, stream>>>(wqkv, wt);
  mha_qkv<<<dim3(128, 3), 256, 0, stream>>>(x, wt, q, k, vt);
  mha_qkconv<<<3072, 512, 0, stream>>>(q, k, c1w, c1b, g1, b1, c2w, c2b, g2, b2, a, partial);
  mha_smpv<<<1536, 256, 0, stream>>>(a, vt, partial, caw1, cab1, caw2, cab2, o);
  mha_proj<<<dim3(128, 3), 256, 0, stream>>>(o, wout, bout, out);
}